// Round 1
// baseline (235.118 us; speedup 1.0000x reference)
//
#include <hip/hip_runtime.h>

// MultiLIF forward: B=32, L=2048, K=512.
// Sequential scan over t per (b,k); parallelism = B*K = 16384 threads = 256 waves.
// Forward-pass numerics: s == s_hard exactly; reset is an exact select.
// Must match reference fp32 rounding: IEEE div, no fma contraction.

#define LL 2048
#define KK 512

constexpr int U = 8;  // time-unroll / prefetch depth

__global__ __launch_bounds__(64, 1) void lif_kernel(const float* __restrict__ I,
                                                    float* __restrict__ spikes,
                                                    float* __restrict__ series) {
#pragma clang fp contract(off)
    const int e = blockIdx.x * 64 + threadIdx.x;   // 0..16383 = b*512 + k
    const int b = e >> 9;
    const int k = e & 511;
    const size_t base = (size_t)b * LL * KK + k;
    const float* Ip = I + base;
    float* sp = spikes + base;
    float* ss = series + base;

    float v = 0.0f, a = 0.0f, n = 0.0f;

    float cur[U], nxt[U];
#pragma unroll
    for (int u = 0; u < U; ++u) cur[u] = Ip[(size_t)u * KK];

    for (int t0 = 0; t0 < LL; t0 += U) {
        if (t0 + U < LL) {
#pragma unroll
            for (int u = 0; u < U; ++u) nxt[u] = Ip[(size_t)(t0 + U + u) * KK];
        }
#pragma unroll
        for (int u = 0; u < U; ++u) {
            const int t = t0 + u;
            const float It = cur[u];
            // v = v - v/TAU + I_t   (IEEE div, separate rounding per op)
            v = v - v / 20.0f + It;
            // th_eff = TH + BETA_ADAPT * a   (mul then add, no fma)
            const float th = 1.0f + 1.5f * a;
            const bool fired = (v >= th);
            const float s = fired ? 1.0f : 0.0f;
            n = n + s;                      // cumulative spike count (exact ints)
            v = fired ? -0.5f : v;          // exact: v*(1-s) + V_RESET*s
            a = a - a / 100.0f + s;         // a = a - a/TAU_ADAPT + s
            __builtin_nontemporal_store(s, sp + (size_t)t * KK);
            __builtin_nontemporal_store(n, ss + (size_t)t * KK);
        }
#pragma unroll
        for (int u = 0; u < U; ++u) cur[u] = nxt[u];
    }
}

extern "C" void kernel_launch(void* const* d_in, const int* in_sizes, int n_in,
                              void* d_out, int out_size, void* d_ws, size_t ws_size,
                              hipStream_t stream) {
    const float* I = (const float*)d_in[0];
    float* spikes = (float*)d_out;
    float* series = (float*)d_out + (size_t)32 * LL * KK;
    lif_kernel<<<256, 64, 0, stream>>>(I, spikes, series);
}

// Round 2
// 118.083 us; speedup vs baseline: 1.9911x; 1.9911x over previous
//
#include <hip/hip_runtime.h>

// MultiLIF forward: B=32, L=2048, K=512.
// Sequential scan over t per (b,k); parallelism = B*K = 16384 threads = 256 waves
// (1 wave/CU — structural). Latency-bound, so: (a) divisions replaced by
// provably-identical f64-multiply rounding (x/20 == (float)((double)x*0.05) for
// ALL f32 x: quotient is never a 24-bit rounding midpoint, margin ~2^-28 vs
// f64 error ~2^-52.5), (b) 4-block rotating register prefetch (distance ~24-32
// steps) to cover ~900-cycle HBM latency with no co-resident wave to hide it.

#define LL 2048
#define KK 512

constexpr int U = 8;   // steps per block
constexpr int NB = 4;  // rotating prefetch buffers (distance ~3-4 blocks)

__global__ __launch_bounds__(64, 1) void lif_kernel(const float* __restrict__ I,
                                                    float* __restrict__ spikes,
                                                    float* __restrict__ series) {
#pragma clang fp contract(off)
    const int e = blockIdx.x * 64 + threadIdx.x;   // 0..16383 = b*512 + k
    const int b = e >> 9;
    const int k = e & 511;
    const size_t base = (size_t)b * LL * KK + k;
    const float* Ip = I + base;
    float* sp = spikes + base;
    float* ss = series + base;

    float v = 0.0f, a = 0.0f, n = 0.0f;

    float q[NB][U];  // all indices compile-time after unrolling
#pragma unroll
    for (int st = 0; st < NB; ++st)
#pragma unroll
        for (int u = 0; u < U; ++u)
            q[st][u] = Ip[(size_t)(st * U + u) * KK];

    for (int t0 = 0; t0 < LL; t0 += NB * U) {
#pragma unroll
        for (int st = 0; st < NB; ++st) {
            const int tb = t0 + st * U;
#pragma unroll
            for (int u = 0; u < U; ++u) {
                const float It = q[st][u];
                // v = (v - v/TAU) + I_t ; v/20 via exact f64-mul rounding
                v = v - (float)((double)v * 0.05) + It;
                const float th = 1.0f + 1.5f * a;    // mul then add, no fma
                const bool fired = (v >= th);
                const float s1 = fired ? 1.0f : 0.0f;
                n = n + s1;                          // cumulative count (exact)
                v = fired ? -0.5f : v;               // exact select
                a = a - (float)((double)a * 0.01) + s1;
                __builtin_nontemporal_store(s1, sp + (size_t)(tb + u) * KK);
                __builtin_nontemporal_store(n, ss + (size_t)(tb + u) * KK);
            }
            // prefetch block tb+NB*U into the buffer just consumed
            if (tb + NB * U < LL) {
#pragma unroll
                for (int u = 0; u < U; ++u)
                    q[st][u] = Ip[(size_t)(tb + NB * U + u) * KK];
            }
        }
    }
}

extern "C" void kernel_launch(void* const* d_in, const int* in_sizes, int n_in,
                              void* d_out, int out_size, void* d_ws, size_t ws_size,
                              hipStream_t stream) {
    const float* I = (const float*)d_in[0];
    float* spikes = (float*)d_out;
    float* series = (float*)d_out + (size_t)32 * LL * KK;
    lif_kernel<<<256, 64, 0, stream>>>(I, spikes, series);
}